// Round 7
// baseline (282.019 us; speedup 1.0000x reference)
//
#include <hip/hip_runtime.h>
#include <stdint.h>

#define SEQ   2048
#define BATCH 4
#define NH    16
#define HD    64
#define DIMN  1024
#define MROWS (BATCH*SEQ)   // 8192

typedef __attribute__((ext_vector_type(8)))  short          bf16x8;
typedef __attribute__((ext_vector_type(8)))  unsigned short ushort8;
typedef __attribute__((ext_vector_type(4)))  float          f32x4;
typedef __attribute__((ext_vector_type(16))) float          f32x16;

static __device__ __forceinline__ unsigned short f2bf(float f) {
    unsigned int u = __builtin_bit_cast(unsigned int, f);
    u += 0x7fffu + ((u >> 16) & 1u);          // RNE
    return (unsigned short)(u >> 16);
}
// RNE-ish (round-half-up) pack: 3 ops
static __device__ __forceinline__ unsigned int pack2bf(float lo, float hi) {
    unsigned int a = __builtin_bit_cast(unsigned int, lo) + 0x8000u;
    unsigned int b = __builtin_bit_cast(unsigned int, hi) + 0x8000u;
    return __builtin_amdgcn_perm(b, a, 0x07060302u);
}
// truncating pack: 1 op (P in [0,1], rel err <= 2^-8, fine for softmax weights)
static __device__ __forceinline__ unsigned int pack2bf_trunc(float lo, float hi) {
    return __builtin_amdgcn_perm(__builtin_bit_cast(unsigned int, hi),
                                 __builtin_bit_cast(unsigned int, lo), 0x07060302u);
}

// ---------------------------------------------------------------- fused prologue
__global__ __launch_bounds__(256) void prologue_kernel(
        const float* __restrict__ x,
        const float* __restrict__ qw, const float* __restrict__ kw,
        const float* __restrict__ vw, const float* __restrict__ ow,
        unsigned short* __restrict__ xb,
        unsigned short* __restrict__ wq, unsigned short* __restrict__ wk,
        unsigned short* __restrict__ wv, unsigned short* __restrict__ wo,
        float* __restrict__ cosT, float* __restrict__ sinT,
        const unsigned char* __restrict__ mask, unsigned long long* __restrict__ m64) {
    const int bx = blockIdx.x, tid = threadIdx.x;
    if (bx < 4096 + 2048) {
        const float* s; unsigned short* d; int i;
        if (bx < 4096) { s = x; d = xb; i = bx * 2048 + tid * 8; }
        else {
            int wb = bx - 4096;
            int wsel = wb >> 9;
            s = wsel == 0 ? qw : (wsel == 1 ? kw : (wsel == 2 ? vw : ow));
            d = wsel == 0 ? wq : (wsel == 1 ? wk : (wsel == 2 ? wv : wo));
            i = (wb & 511) * 2048 + tid * 8;
        }
        float4 a = *(const float4*)(s + i);
        float4 b = *(const float4*)(s + i + 4);
        ushort8 o;
        o[0]=f2bf(a.x); o[1]=f2bf(a.y); o[2]=f2bf(a.z); o[3]=f2bf(a.w);
        o[4]=f2bf(b.x); o[5]=f2bf(b.y); o[6]=f2bf(b.z); o[7]=f2bf(b.w);
        *(ushort8*)(d + i) = o;
    } else if (bx < 6400) {
        int idx = (bx - 6144) * 256 + tid;        // SEQ*32
        int s = idx >> 5, j = idx & 31;
        float t = (float)(2 * j) / 64.0f;
        float freq = 1.0f / powf(10000.0f, t);
        float ang  = (float)s * freq;
        cosT[idx] = cosf(ang);
        sinT[idx] = sinf(ang);
    } else {
        if (tid < 128) {
            int b = tid >> 5, kt = tid & 31;
            const unsigned char* p = mask + b * SEQ + kt * 64;
            unsigned long long v = 0;
            for (int j = 0; j < 64; j++) v |= (unsigned long long)(p[j] != 0) << j;
            m64[tid] = v;
        }
    }
}

// ---------------------------------------------------------------- fused Q,K,V^T GEMM
// (unchanged from R6) LDS double-buffer + early stage; chunk XOR swizzle.
__global__ __launch_bounds__(256) void gemm_qkvt(const unsigned short* __restrict__ X,
        const unsigned short* __restrict__ Wq, const unsigned short* __restrict__ Wk,
        const unsigned short* __restrict__ Wv,
        const float* __restrict__ bq, const float* __restrict__ bk, const float* __restrict__ bv,
        unsigned short* __restrict__ Qo, unsigned short* __restrict__ Ko, unsigned short* __restrict__ Vto,
        const float* __restrict__ cosT, const float* __restrict__ sinT) {
    __shared__ __align__(16) unsigned short As0[128 * 32];
    __shared__ __align__(16) unsigned short Bs0[128 * 32];
    __shared__ __align__(16) unsigned short As1[128 * 32];
    __shared__ __align__(16) unsigned short Bs1[128 * 32];
    const int which = blockIdx.x >> 3;
    const int tid  = threadIdx.x;
    const int wid  = tid >> 6, lane = tid & 63;
    const int quad = lane >> 4, l15 = lane & 15;
    const int wm   = wid >> 1,  wn  = wid & 1;

    const unsigned short *Ag, *Bg;
    int m0, n0;
    if (which < 2) {
        m0 = blockIdx.y * 128;                 // token rows
        n0 = (blockIdx.x & 7) * 128;           // embed cols
        Ag = X;  Bg = which == 0 ? Wq : Wk;
    } else {
        m0 = (blockIdx.x & 7) * 128;           // e rows
        n0 = blockIdx.y * 128;                 // token rows
        Ag = Wv; Bg = X;
    }

    f32x4 acc[4][4];
#pragma unroll
    for (int i = 0; i < 4; i++)
#pragma unroll
        for (int j = 0; j < 4; j++) acc[i][j] = (f32x4)0.0f;

    const int rb = wid * 32 + (lane >> 2);
    const int cb = (((lane & 3) ^ ((lane >> 3) & 3)) * 8);
    const int rq = (quad ^ ((l15 >> 1) & 3)) * 8;

#define GSTAGE(BA, BB, KK) do {                                                             \
    _Pragma("unroll")                                                                       \
    for (int i_ = 0; i_ < 2; i_++) {                                                        \
        const unsigned short* ga_ = Ag + (size_t)(m0 + rb + i_ * 16) * DIMN + (KK) + cb;    \
        __builtin_amdgcn_global_load_lds((const __attribute__((address_space(1))) void*)ga_,\
            (__attribute__((address_space(3))) void*)&BA[(wid * 32 + i_ * 16) * 32], 16, 0, 0);\
        const unsigned short* gb_ = Bg + (size_t)(n0 + rb + i_ * 16) * DIMN + (KK) + cb;    \
        __builtin_amdgcn_global_load_lds((const __attribute__((address_space(1))) void*)gb_,\
            (__attribute__((address_space(3))) void*)&BB[(wid * 32 + i_ * 16) * 32], 16, 0, 0);\
    } } while (0)

#define GCOMP(BA, BB) do {                                                                  \
    bf16x8 af_[4], bf_[4];                                                                  \
    _Pragma("unroll")                                                                       \
    for (int f_ = 0; f_ < 4; f_++) af_[f_] = *(const bf16x8*)&BA[(wm * 64 + f_ * 16 + l15) * 32 + rq]; \
    _Pragma("unroll")                                                                       \
    for (int f_ = 0; f_ < 4; f_++) bf_[f_] = *(const bf16x8*)&BB[(wn * 64 + f_ * 16 + l15) * 32 + rq]; \
    _Pragma("unroll")                                                                       \
    for (int fm_ = 0; fm_ < 4; fm_++)                                                       \
        _Pragma("unroll")                                                                   \
        for (int fn_ = 0; fn_ < 4; fn_++)                                                   \
            acc[fm_][fn_] = __builtin_amdgcn_mfma_f32_16x16x32_bf16(af_[fm_], bf_[fn_], acc[fm_][fn_], 0, 0, 0); \
    } while (0)

    GSTAGE(As0, Bs0, 0);
    for (int k0 = 0; k0 < DIMN; k0 += 64) {
        __syncthreads();                           // As0/Bs0 ready
        GSTAGE(As1, Bs1, k0 + 32);                 // issue next into other buffer
        GCOMP(As0, Bs0);
        __syncthreads();                           // As1/Bs1 ready
        if (k0 + 64 < DIMN) GSTAGE(As0, Bs0, k0 + 64);
        GCOMP(As1, Bs1);
    }

    if (which < 2) {                            // Q or K: +bias, scale, RoPE, [B,H,S,D]
        const float* bias   = which == 0 ? bq : bk;
        unsigned short* Out = which == 0 ? Qo : Ko;
        const float scale = which == 0 ? 0.18033688011112042f : 1.0f;  // 0.125*log2e
        float bv4[4];
#pragma unroll
        for (int fn = 0; fn < 4; fn++) bv4[fn] = bias[n0 + wn * 64 + fn * 16 + l15];
        const int h = (n0 >> 6) + wn;
#pragma unroll
        for (int fm = 0; fm < 4; fm++)
#pragma unroll
            for (int r = 0; r < 4; r++) {
                int mrow = m0 + wm * 64 + fm * 16 + quad * 4 + r;
                int b = mrow >> 11, s = mrow & (SEQ - 1);
                unsigned short* orow = Out + ((size_t)(b * NH + h) * SEQ + s) * HD;
                float v0 = (acc[fm][0][r] + bv4[0]) * scale;
                float v1 = (acc[fm][1][r] + bv4[1]) * scale;
                float v2 = (acc[fm][2][r] + bv4[2]) * scale;
                float v3 = (acc[fm][3][r] + bv4[3]) * scale;
                int d0 = l15, d1 = 16 + l15;
                float c0 = cosT[s * 32 + d0], s0 = sinT[s * 32 + d0];
                float c1 = cosT[s * 32 + d1], s1 = sinT[s * 32 + d1];
                orow[d0]      = f2bf(v0 * c0 - v2 * s0);
                orow[d0 + 32] = f2bf(v0 * s0 + v2 * c0);
                orow[d1]      = f2bf(v1 * c1 - v3 * s1);
                orow[d1 + 32] = f2bf(v1 * s1 + v3 * c1);
            }
    } else {                                    // V^T: [B,H,D,S]
        float4 bb[4];
#pragma unroll
        for (int fm = 0; fm < 4; fm++)
            bb[fm] = *(const float4*)&bv[m0 + wm * 64 + fm * 16 + quad * 4];
        const int b     = n0 >> 11;
        const int sbase = (n0 & (SEQ - 1)) + wn * 64 + l15;
#pragma unroll
        for (int fm = 0; fm < 4; fm++)
#pragma unroll
            for (int r = 0; r < 4; r++) {
                int e = m0 + wm * 64 + fm * 16 + quad * 4 + r;
                float bval = r == 0 ? bb[fm].x : (r == 1 ? bb[fm].y : (r == 2 ? bb[fm].z : bb[fm].w));
                unsigned short* row = Vto + ((size_t)(b * NH + (e >> 6)) * HD + (e & 63)) * SEQ + sbase;
#pragma unroll
                for (int fn = 0; fn < 4; fn++)
                    row[fn * 16] = f2bf(acc[fm][fn][r] + bval);
            }
    }
#undef GSTAGE
#undef GCOMP
}

// ---------------------------------------------------------------- output-proj GEMM (fp32 out)
__global__ __launch_bounds__(256) void gemm_bt(const unsigned short* __restrict__ A,
                                               const unsigned short* __restrict__ W,
                                               const float* __restrict__ bias,
                                               float* __restrict__ out) {
    __shared__ __align__(16) unsigned short As0[128 * 32];
    __shared__ __align__(16) unsigned short Bs0[128 * 32];
    __shared__ __align__(16) unsigned short As1[128 * 32];
    __shared__ __align__(16) unsigned short Bs1[128 * 32];
    const int tid  = threadIdx.x;
    const int wid  = tid >> 6, lane = tid & 63;
    const int quad = lane >> 4, l15 = lane & 15;
    const int wm   = wid >> 1,  wn  = wid & 1;
    const int m0   = blockIdx.y * 128, n0 = blockIdx.x * 128;

    f32x4 acc[4][4];
#pragma unroll
    for (int i = 0; i < 4; i++)
#pragma unroll
        for (int j = 0; j < 4; j++) acc[i][j] = (f32x4)0.0f;

    const int rb = wid * 32 + (lane >> 2);
    const int cb = (((lane & 3) ^ ((lane >> 3) & 3)) * 8);
    const int rq = (quad ^ ((l15 >> 1) & 3)) * 8;

#define GSTAGE(BA, BB, KK) do {                                                             \
    _Pragma("unroll")                                                                       \
    for (int i_ = 0; i_ < 2; i_++) {                                                        \
        const unsigned short* ga_ = A + (size_t)(m0 + rb + i_ * 16) * DIMN + (KK) + cb;     \
        __builtin_amdgcn_global_load_lds((const __attribute__((address_space(1))) void*)ga_,\
            (__attribute__((address_space(3))) void*)&BA[(wid * 32 + i_ * 16) * 32], 16, 0, 0);\
        const unsigned short* gb_ = W + (size_t)(n0 + rb + i_ * 16) * DIMN + (KK) + cb;     \
        __builtin_amdgcn_global_load_lds((const __attribute__((address_space(1))) void*)gb_,\
            (__attribute__((address_space(3))) void*)&BB[(wid * 32 + i_ * 16) * 32], 16, 0, 0);\
    } } while (0)

#define GCOMP(BA, BB) do {                                                                  \
    bf16x8 af_[4], bf_[4];                                                                  \
    _Pragma("unroll")                                                                       \
    for (int f_ = 0; f_ < 4; f_++) af_[f_] = *(const bf16x8*)&BA[(wm * 64 + f_ * 16 + l15) * 32 + rq]; \
    _Pragma("unroll")                                                                       \
    for (int f_ = 0; f_ < 4; f_++) bf_[f_] = *(const bf16x8*)&BB[(wn * 64 + f_ * 16 + l15) * 32 + rq]; \
    _Pragma("unroll")                                                                       \
    for (int fm_ = 0; fm_ < 4; fm_++)                                                       \
        _Pragma("unroll")                                                                   \
        for (int fn_ = 0; fn_ < 4; fn_++)                                                   \
            acc[fm_][fn_] = __builtin_amdgcn_mfma_f32_16x16x32_bf16(af_[fm_], bf_[fn_], acc[fm_][fn_], 0, 0, 0); \
    } while (0)

    GSTAGE(As0, Bs0, 0);
    for (int k0 = 0; k0 < DIMN; k0 += 64) {
        __syncthreads();
        GSTAGE(As1, Bs1, k0 + 32);
        GCOMP(As0, Bs0);
        __syncthreads();
        if (k0 + 64 < DIMN) GSTAGE(As0, Bs0, k0 + 64);
        GCOMP(As1, Bs1);
    }

    float bv4[4];
#pragma unroll
    for (int fn = 0; fn < 4; fn++) bv4[fn] = bias[n0 + wn * 64 + fn * 16 + l15];
#pragma unroll
    for (int fm = 0; fm < 4; fm++)
#pragma unroll
        for (int r = 0; r < 4; r++) {
            int mrow = m0 + wm * 64 + fm * 16 + quad * 4 + r;
            float* orow = out + (size_t)mrow * DIMN + n0 + wn * 64;
#pragma unroll
            for (int fn = 0; fn < 4; fn++) orow[fn * 16 + l15] = acc[fm][fn][r] + bv4[fn];
        }
#undef GSTAGE
#undef GCOMP
}

// ---------------------------------------------------------------- flash attention v14
// v13 counters: VALUBusy 44 + MfmaUtil 33 = 77% jointly; per-CU demand: VALU
// ~90K cyc (exp2-dominated), MFMA ~66K, measured 204K -> ~2x lost to failed
// VALU<->MFMA overlap. Cause: per-half chain QK->softmax->PV is issue-order
// serialized, and the s_setprio pairs fence the scheduler from interleaving
// across halves (m190: setprio on barrier-locked waves <= 0).
// v14: explicit cross-half software pipeline, NO setprio:
//   kA0|QK(0) -> kA1|QK(1) -> softmax(0) [VALU issues under QK(1) execution]
//   -> vf0|PV(0) -> softmax(1) [under PV(0)] -> vf1|PV(1).
// Pure reorder: same layouts, same barriers, same math. Peak liveness ~115
// VGPR < 128 cap (vf just-in-time; kA0 dead before kA1 lives).
__global__ __launch_bounds__(256, 4) void attn_kernel(const unsigned short* __restrict__ Q,
                                                      const unsigned short* __restrict__ K,
                                                      const unsigned short* __restrict__ Vt,
                                                      const unsigned long long* __restrict__ M64,
                                                      unsigned short* __restrict__ Ob) {
    __shared__ __align__(16) unsigned short Kls[64 * 64];   // 8 KiB [token][k]
    __shared__ __align__(16) unsigned short Vls[64 * 64];   // 8 KiB [d][token]

    const int tid  = threadIdx.x;
    const int wid  = tid >> 6, lane = tid & 63;
    const int hi   = lane >> 5, l31 = lane & 31, l7 = lane & 7;
    // XCD-aware swizzle: xcd = bid&7; each XCD owns 8 complete (b,h) groups.
    const int bid = blockIdx.x;
    const int bh  = (bid & 7) * 8 + (bid >> 7);
    const int qt  = (bid >> 3) & 15;
    const int b = bh >> 4, h = bh & 15;
    const int q0 = qt * 128;

    // persistent Q fragments (B-operand): q = q0 + wid*32 + l31,
    // k = ksub*16 + hi*8 + e
    bf16x8 qB[4];
    {
        const unsigned short* qrow = Q + ((size_t)bh * SEQ + q0 + wid * 32 + l31) * HD + hi * 8;
#pragma unroll
        for (int ks = 0; ks < 4; ks++)
            qB[ks] = __builtin_bit_cast(bf16x8, *(const uint4*)(qrow + ks * 16));
    }

    f32x16 Oa[2];                 // O^T tiles: d = dt*32 + (r&3)+8*(r>>2)+4*hi, q = l31
    Oa[0] = (f32x16)0.0f;
    Oa[1] = (f32x16)0.0f;
    float ls = 0.0f;

    const unsigned long long* Mrow = M64 + b * (SEQ / 64);

    // staging bases: each wave stages rows [wid*16, wid*16+16) of both tiles;
    // lane -> row += (lane>>3), source granule pre-swizzled (rule 21)
    const int srow = lane >> 3;                              // 0..7
    const int sgr  = ((lane & 7) ^ ((lane >> 3) & 7)) * 8;   // swizzled 16B granule
    const unsigned short* Kg = K  + (size_t)bh * SEQ * HD;
    const unsigned short* Vg = Vt + (size_t)bh * HD * SEQ;
    const unsigned short* Kb0 = Kg + (size_t)(wid * 16 + srow) * HD + sgr;
    const unsigned short* Vb0 = Vg + (size_t)(wid * 16 + srow) * SEQ + sgr;

    // per-half helpers -------------------------------------------------------
#define QK_HALF(H2, ST) do {                                                             \
    bf16x8 kA_[4];                                                                       \
    _Pragma("unroll")                                                                    \
    for (int ks_ = 0; ks_ < 4; ks_++)                                                    \
        kA_[ks_] = *(const bf16x8*)&Kls[((H2) * 32 + l31) * 64 + ((((ks_) << 1) + hi) ^ l7) * 8]; \
    _Pragma("unroll")                                                                    \
    for (int ks_ = 0; ks_ < 4; ks_++)                                                    \
        ST = __builtin_amdgcn_mfma_f32_32x32x16_bf16(kA_[ks_], qB[ks_], ST, 0, 0, 0);    \
    } while (0)

#define SM_HALF(ST, MH, PB) do {                                                         \
    if (MH) {                                                                            \
        _Pragma("unroll")                                                                \
        for (int r_ = 0; r_ < 16; r_++) {                                                \
            int kk_ = (r_ & 3) + ((r_ >> 2) << 3) + (hi << 2);                           \
            if (((MH) >> kk_) & 1u) ST[r_] = -1e9f;                                      \
        }                                                                                \
    }                                                                                    \
    float p_[16];                                                                        \
    _Pragma("unroll")                                                                    \
    for (int r_ = 0; r_ < 16; r_++) p_[r_] = __builtin_amdgcn_exp2f(ST[r_]);             \
    ls += (((p_[0] + p_[1]) + (p_[2] + p_[3])) + ((p_[4] + p_[5]) + (p_[6] + p_[7])))    \
        + (((p_[8] + p_[9]) + (p_[10] + p_[11])) + ((p_[12] + p_[13]) + (p_[14] + p_[15]))); \
    unsigned int w000 = pack2bf_trunc(p_[0],  p_[1]);                                    \
    unsigned int w001 = pack2bf_trunc(p_[2],  p_[3]);                                    \
    unsigned int w010 = pack2bf_trunc(p_[4],  p_[5]);                                    \
    unsigned int w011 = pack2bf_trunc(p_[6],  p_[7]);                                    \
    unsigned int w100 = pack2bf_trunc(p_[8],  p_[9]);                                    \
    unsigned int w101 = pack2bf_trunc(p_[10], p_[11]);                                   \
    unsigned int w110 = pack2bf_trunc(p_[12], p_[13]);                                   \
    unsigned int w111 = pack2bf_trunc(p_[14], p_[15]);                                   \
    _Pragma("unroll")                                                                    \
    for (int ks_ = 0; ks_ < 2; ks_++) {                                                  \
        unsigned int own0 = ks_ == 0 ? (hi ? w010 : w000) : (hi ? w110 : w100);          \
        unsigned int own1 = ks_ == 0 ? (hi ? w011 : w001) : (hi ? w111 : w101);          \
        unsigned int oth0 = ks_ == 0 ? (hi ? w000 : w010) : (hi ? w100 : w110);          \
        unsigned int oth1 = ks_ == 0 ? (hi ? w001 : w011) : (hi ? w101 : w111);          \
        unsigned int r0 = (unsigned int)__shfl_xor((int)oth0, 32);                       \
        unsigned int r1 = (unsigned int)__shfl_xor((int)oth1, 32);                       \
        uint4 pw;                                                                        \
        pw.x = hi ? r0 : own0;                                                           \
        pw.y = hi ? r1 : own1;                                                           \
        pw.z = hi ? own0 : r0;                                                           \
        pw.w = hi ? own1 : r1;                                                           \
        PB[ks_] = __builtin_bit_cast(bf16x8, pw);                                        \
    } } while (0)

#define PV_HALF(H2, PB) do {                                                             \
    _Pragma("unroll")                                                                    \
    for (int dt_ = 0; dt_ < 2; dt_++)                                                    \
        _Pragma("unroll")                                                                \
        for (int kv_ = 0; kv_ < 2; kv_++) {                                              \
            bf16x8 vA_ = *(const bf16x8*)&Vls[(dt_ * 32 + l31) * 64 +                    \
                            ((((H2) << 2) + (kv_ << 1) + hi) ^ l7) * 8];                 \
            Oa[dt_] = __builtin_amdgcn_mfma_f32_32x32x16_bf16(vA_, PB[kv_], Oa[dt_], 0, 0, 0); \
        } } while (0)

    for (int kt = 0; kt < SEQ / 64; kt++) {
        const int k0 = kt * 64;
#pragma unroll
        for (int j = 0; j < 2; j++) {
            __builtin_amdgcn_global_load_lds(
                (const __attribute__((address_space(1))) void*)(Kb0 + (size_t)(k0 + j * 8) * HD),
                (__attribute__((address_space(3))) void*)&Kls[(wid * 16 + j * 8) * 64], 16, 0, 0);
            __builtin_amdgcn_global_load_lds(
                (const __attribute__((address_space(1))) void*)(Vb0 + (size_t)(j * 8) * SEQ + k0),
                (__attribute__((address_space(3))) void*)&Vls[(wid * 16 + j * 8) * 64], 16, 0, 0);
        }
        unsigned long long mb = Mrow[kt];
        __syncthreads();                 // drains vmcnt: tiles visible to all waves

        unsigned int mh0 = (unsigned int)mb;
        unsigned int mh1 = (unsigned int)(mb >> 32);

        // cross-half pipeline: both QK chains issued back-to-back; each
        // softmax's VALU burst issues while the other half's MFMAs execute.
        f32x16 st0 = (f32x16)0.0f;
        QK_HALF(0, st0);
        f32x16 st1 = (f32x16)0.0f;
        QK_HALF(1, st1);

        bf16x8 pB0[2];
        SM_HALF(st0, mh0, pB0);          // issues under QK(1) execution
        PV_HALF(0, pB0);

        bf16x8 pB1[2];
        SM_HALF(st1, mh1, pB1);          // issues under PV(0) execution
        PV_HALF(1, pB1);

        __syncthreads();                 // before next tile overwrites tiles
    }
#undef QK_HALF
#undef SM_HALF
#undef PV_HALF

    float lsum = ls + __shfl_xor(ls, 32);
    float linv = 1.0f / lsum;

    const int s = q0 + wid * 32 + l31;
    unsigned short* orow = Ob + ((size_t)b * SEQ + s) * DIMN + h * HD + hi * 4;
#pragma unroll
    for (int dt = 0; dt < 2; dt++)
#pragma unroll
        for (int rq = 0; rq < 4; rq++) {
            uint2 w;
            w.x = pack2bf(Oa[dt][rq * 4 + 0] * linv, Oa[dt][rq * 4 + 1] * linv);
            w.y = pack2bf(Oa[dt][rq * 4 + 2] * linv, Oa[dt][rq * 4 + 3] * linv);
            *(uint2*)&orow[dt * 32 + rq * 8] = w;
        }
}

// ---------------------------------------------------------------- launch
extern "C" void kernel_launch(void* const* d_in, const int* in_sizes, int n_in,
                              void* d_out, int out_size, void* d_ws, size_t ws_size,
                              hipStream_t stream) {
    (void)in_sizes; (void)n_in; (void)out_size; (void)ws_size;
    const float* x  = (const float*)d_in[0];
    const unsigned char* mask = (const unsigned char*)d_in[1];
    const float* q_w = (const float*)d_in[2];
    const float* q_b = (const float*)d_in[3];
    const float* k_w = (const float*)d_in[4];
    const float* k_b = (const float*)d_in[5];
    const float* v_w = (const float*)d_in[6];
    const float* v_b = (const float*)d_in[7];
    const float* o_w = (const float*)d_in[8];
    const float* o_b = (const float*)d_in[9];
    float* out = (float*)d_out;

    char* w = (char*)d_ws;
    unsigned short* xb = (unsigned short*)w;                        // 16 MiB (reused as attn output)
    unsigned short* wq = (unsigned short*)(w + (16u << 20));        // 4 x 2 MiB
    unsigned short* wk = wq + (1u << 20);
    unsigned short* wv = wk + (1u << 20);
    unsigned short* wo = wv + (1u << 20);
    float* cosT = (float*)(w + (24u << 20));                        // 256 KiB
    float* sinT = cosT + SEQ * 32;
    unsigned long long* m64 = (unsigned long long*)(w + (24u << 20) + (1u << 19)); // 1 KiB
    unsigned short* Qb  = (unsigned short*)(w + (25u << 20));       // 3 x 16 MiB
    unsigned short* Kb  = Qb + (8u << 20);
    unsigned short* Vtb = Kb + (8u << 20);
    unsigned short* Ob  = xb;                                       // reuse x's slot

    prologue_kernel<<<dim3(6401), 256, 0, stream>>>(x, q_w, k_w, v_w, o_w,
                                                    xb, wq, wk, wv, wo,
                                                    cosT, sinT, mask, m64);

    gemm_qkvt<<<dim3(24, 64), 256, 0, stream>>>(xb, wq, wk, wv, q_b, k_b, v_b,
                                                Qb, Kb, Vtb, cosT, sinT);

    attn_kernel<<<dim3(1024), 256, 0, stream>>>(Qb, Kb, Vtb, m64, Ob);

    gemm_bt<<<dim3(DIMN / 128, MROWS / 128), 256, 0, stream>>>(Ob, wo, o_b, out);
}